// Round 1
// baseline (265.239 us; speedup 1.0000x reference)
//
#include <hip/hip_runtime.h>
#include <hip/hip_fp16.h>

// Problem geometry: inputs (B=2, D=64, H=64, W=64, C=32) fp32, C innermost.
// Pass1: Sobel (VALID) -> mag = sqrt(gx^2+gy^2+gz^2) at 62^3 per (b,c)
// Pass2: Sobel on mag -> out = sqrt(gx^2+gy^2) + gz^2 at 60^3
// Result: mean(|out_pred - out_hr|) over 2*32*60^3 = 13,824,000 elems.
//
// R5: batch-merged launches. R4 counters: all pipes <35% busy, occupancy 31%
// (grid supplied only 16 waves/CU vs the 32 that VGPR=64 allows), and ~45us of
// inter-dispatch gaps in the 5-kernel chain. Fix: fold the b-loop into grid.z
// (P1: 2048 blocks = exactly 8 blocks/CU = full residency; P2: 1440 blocks),
// and fold finalize into P2 via a last-block device-scope atomic pattern.
// Chain is now P1 -> P2 (one transition). Falls back to the per-batch path if
// ws_size < ~58.3 MB (4 fp16 mag buffers).

constexpr int BDIM = 256;
constexpr size_t IN_B = 8388608;   // 64*64*64*32 elements per batch
constexpr int IN_D = 131072;       // 64*64*32
constexpr int IN_H = 2048;         // 64*32
constexpr int M = 62;              // mag spatial dim
constexpr int F = 60;              // final spatial dim
constexpr int C = 32;
constexpr int MROW = M * C;                      // 1984
constexpr size_t MAGSZ = (size_t)M * M * MROW;   // halves per buffer
constexpr size_t PLANE = (size_t)M * MROW;       // halves per mag z-plane
constexpr unsigned NPART = 1440;                 // total partials (both batches)

__device__ __forceinline__ float2 ld2(const float* p) {
    return *reinterpret_cast<const float2*>(p);
}
__device__ __forceinline__ float2 ldh2(const __half* p) {
    return __half22float2(*reinterpret_cast<const __half2*>(p));
}

// ================= Pass 1: input -> fp16 magnitude, z-streamed =================
struct P1W { float2 A[4], B[4], C[4]; };   // per-plane partials for 4 output rows

__device__ __forceinline__ void p1_plane(const float* __restrict__ col, size_t zoff,
                                         const int jr[6], P1W& W)
{
    float2 SX[6], DX[6];
#pragma unroll
    for (int j = 0; j < 6; ++j) {
        const float* p = col + zoff + jr[j];
        float2 a = ld2(p), b = ld2(p + C), c = ld2(p + 2 * C);
        SX[j] = make_float2(a.x + 2.f * b.x + c.x, a.y + 2.f * b.y + c.y);
        DX[j] = make_float2(c.x - a.x, c.y - a.y);
    }
#pragma unroll
    for (int k = 0; k < 4; ++k) {
        W.A[k] = make_float2(SX[k].x + 2.f * SX[k+1].x + SX[k+2].x,
                             SX[k].y + 2.f * SX[k+1].y + SX[k+2].y);
        W.B[k] = make_float2(SX[k+2].x - SX[k].x, SX[k+2].y - SX[k].y);
        W.C[k] = make_float2(DX[k].x + 2.f * DX[k+1].x + DX[k+2].x,
                             DX[k].y + 2.f * DX[k+1].y + DX[k+2].y);
    }
}

__device__ __forceinline__ void p1_emit(const P1W& W0, const P1W& W1, const P1W& W2,
                                        __half* __restrict__ mag, size_t cb,
                                        int z, int y0, int kmax, bool xok)
{
    if (!xok) return;
#pragma unroll
    for (int k = 0; k < 4; ++k) {
        if (k < kmax) {
            float gxx = W2.A[k].x - W0.A[k].x;
            float gxy = W2.A[k].y - W0.A[k].y;
            float gyx = W0.B[k].x + 2.f * W1.B[k].x + W2.B[k].x;
            float gyy = W0.B[k].y + 2.f * W1.B[k].y + W2.B[k].y;
            float gzx = W0.C[k].x + 2.f * W1.C[k].x + W2.C[k].x;
            float gzy = W0.C[k].y + 2.f * W1.C[k].y + W2.C[k].y;
            float mx = sqrtf(gxx * gxx + gyx * gyx + gzx * gzx);
            float my = sqrtf(gxy * gxy + gyy * gyy + gzy * gzy);
            *reinterpret_cast<__half2*>(mag + ((size_t)z * M + (y0 + k)) * MROW + cb)
                = __floats2half2_rn(mx, my);
        }
    }
}

// grid: (64, 8, 2*nb). blockIdx.z = (b-b0)*2 + isHr. magBStride = per-batch
// buffer stride in halves (0 in the fallback path where nb==1).
__global__ __launch_bounds__(BDIM) void sobel_mag_stream(
    const float* __restrict__ pred, const float* __restrict__ hr,
    __half* __restrict__ magP, __half* __restrict__ magH,
    size_t magBStride, int b0, unsigned* __restrict__ counter)
{
    // zero the last-block counter exactly once per kernel_launch call (P2 only
    // runs after this dispatch fully drains, so this is race-free)
    if (b0 == 0 && blockIdx.x == 0 && blockIdx.y == 0 && blockIdx.z == 0 &&
        threadIdx.x == 0)
        *counter = 0u;

    const int xt = blockIdx.x & 3, yt = blockIdx.x >> 2;   // grid.x = 64
    const int zc = blockIdx.y;                             // [0,8)
    const int bz = blockIdx.z;
    const int b  = b0 + (bz >> 1);
    const float* __restrict__ in  = (bz & 1) ? hr : pred;
    __half*      __restrict__ mag = ((bz & 1) ? magH : magP)
                                    + (size_t)(bz >> 1) * magBStride;

    const int y0 = yt * 4;
    const int z0 = zc * 8;
    const int zn = min(8, M - z0);        // 8 or 6
    const int kmax = min(4, M - y0);      // 4 or (last tile) 2
    const int xraw = xt * 16 + (threadIdx.x >> 4);
    const bool xok = xraw < M;
    const int x = min(xraw, M - 1);
    const int c2 = (threadIdx.x & 15) << 1;

    int jr[6];
#pragma unroll
    for (int j = 0; j < 6; ++j) jr[j] = min(y0 + j, 63) * IN_H;

    const float* col = in + (size_t)b * IN_B + (size_t)x * C + c2;
    const size_t cb = (size_t)x * C + c2;

    P1W W0, W1, W2;
    p1_plane(col, (size_t)(z0 + 0) * IN_D, jr, W0);
    p1_plane(col, (size_t)(z0 + 1) * IN_D, jr, W1);
    int z = 0;
    while (true) {
        p1_plane(col, (size_t)(z0 + z + 2) * IN_D, jr, W2);
        p1_emit(W0, W1, W2, mag, cb, z0 + z, y0, kmax, xok);
        if (++z >= zn) break;
        p1_plane(col, (size_t)(z0 + z + 2) * IN_D, jr, W0);
        p1_emit(W1, W2, W0, mag, cb, z0 + z, y0, kmax, xok);
        if (++z >= zn) break;
        p1_plane(col, (size_t)(z0 + z + 2) * IN_D, jr, W1);
        p1_emit(W2, W0, W1, mag, cb, z0 + z, y0, kmax, xok);
        if (++z >= zn) break;
    }
}

// ============ Pass 2: mag -> final, diff, partial sums, z-streamed ============
struct P2W { float2 A[2], B[2], C[2]; };

__device__ __forceinline__ void p2_plane(const __half* __restrict__ col, size_t zoff, P2W& W)
{
    float2 SX[4], DX[4];
#pragma unroll
    for (int j = 0; j < 4; ++j) {
        const __half* p = col + zoff + (size_t)j * MROW;
        float2 a = ldh2(p), b = ldh2(p + C), c = ldh2(p + 2 * C);
        SX[j] = make_float2(a.x + 2.f * b.x + c.x, a.y + 2.f * b.y + c.y);
        DX[j] = make_float2(c.x - a.x, c.y - a.y);
    }
#pragma unroll
    for (int k = 0; k < 2; ++k) {
        W.A[k] = make_float2(SX[k].x + 2.f * SX[k+1].x + SX[k+2].x,
                             SX[k].y + 2.f * SX[k+1].y + SX[k+2].y);
        W.B[k] = make_float2(SX[k+2].x - SX[k].x, SX[k+2].y - SX[k].y);
        W.C[k] = make_float2(DX[k].x + 2.f * DX[k+1].x + DX[k+2].x,
                             DX[k].y + 2.f * DX[k+1].y + DX[k+2].y);
    }
}

__device__ __forceinline__ void p2_emit(const P2W& P0, const P2W& P1, const P2W& P2,
                                        const P2W& H0, const P2W& H1, const P2W& H2,
                                        float& acc)
{
#pragma unroll
    for (int k = 0; k < 2; ++k) {
        float gxPx = P2.A[k].x - P0.A[k].x;
        float gxPy = P2.A[k].y - P0.A[k].y;
        float gyPx = P0.B[k].x + 2.f * P1.B[k].x + P2.B[k].x;
        float gyPy = P0.B[k].y + 2.f * P1.B[k].y + P2.B[k].y;
        float gzPx = P0.C[k].x + 2.f * P1.C[k].x + P2.C[k].x;
        float gzPy = P0.C[k].y + 2.f * P1.C[k].y + P2.C[k].y;
        float gxHx = H2.A[k].x - H0.A[k].x;
        float gxHy = H2.A[k].y - H0.A[k].y;
        float gyHx = H0.B[k].x + 2.f * H1.B[k].x + H2.B[k].x;
        float gyHy = H0.B[k].y + 2.f * H1.B[k].y + H2.B[k].y;
        float gzHx = H0.C[k].x + 2.f * H1.C[k].x + H2.C[k].x;
        float gzHy = H0.C[k].y + 2.f * H1.C[k].y + H2.C[k].y;
        float oPx = sqrtf(gxPx * gxPx + gyPx * gyPx) + gzPx * gzPx;
        float oPy = sqrtf(gxPy * gxPy + gyPy * gyPy) + gzPy * gzPy;
        float oHx = sqrtf(gxHx * gxHx + gyHx * gyHx) + gzHx * gzHx;
        float oHy = sqrtf(gxHy * gxHy + gyHy * gyHy) + gzHy * gzHy;
        acc += fabsf(oPx - oHx) + fabsf(oPy - oHy);
    }
}

// grid: (120, 6, nb). blockIdx.z = b - b0. Last block (device-wide, counted via
// agent-scope atomic) performs the final 1440-partial reduction and writes out.
__global__ __launch_bounds__(BDIM) void sobel2_stream(
    const __half* __restrict__ magP, const __half* __restrict__ magH,
    size_t magBStride, int b0,
    float* __restrict__ partial, unsigned* __restrict__ counter,
    float* __restrict__ out)
{
    const int xt = blockIdx.x & 3, yt = blockIdx.x >> 2;   // grid.x = 120
    const int zc = blockIdx.y;                             // [0,6)
    const int bb = blockIdx.z;
    const int b  = b0 + bb;
    const int y0 = yt * 2;
    const int z0 = zc * 10;
    const int xraw = xt * 16 + (threadIdx.x >> 4);
    const bool xok = xraw < F;
    const int x = min(xraw, F - 1);
    const int c2 = (threadIdx.x & 15) << 1;

    const size_t colo = (size_t)y0 * MROW + (size_t)x * C + c2;
    const __half* colP = magP + (size_t)bb * magBStride + colo;
    const __half* colH = magH + (size_t)bb * magBStride + colo;

    P2W P0, P1, P2, H0, H1, H2;
    p2_plane(colP, (size_t)(z0 + 0) * PLANE, P0);
    p2_plane(colH, (size_t)(z0 + 0) * PLANE, H0);
    p2_plane(colP, (size_t)(z0 + 1) * PLANE, P1);
    p2_plane(colH, (size_t)(z0 + 1) * PLANE, H1);
    float acc = 0.f;
    int z = 0;
    while (true) {
        p2_plane(colP, (size_t)(z0 + z + 2) * PLANE, P2);
        p2_plane(colH, (size_t)(z0 + z + 2) * PLANE, H2);
        if (xok) p2_emit(P0, P1, P2, H0, H1, H2, acc);
        if (++z >= 10) break;
        p2_plane(colP, (size_t)(z0 + z + 2) * PLANE, P0);
        p2_plane(colH, (size_t)(z0 + z + 2) * PLANE, H0);
        if (xok) p2_emit(P1, P2, P0, H1, H2, H0, acc);
        if (++z >= 10) break;
        p2_plane(colP, (size_t)(z0 + z + 2) * PLANE, P1);
        p2_plane(colH, (size_t)(z0 + z + 2) * PLANE, H1);
        if (xok) p2_emit(P2, P0, P1, H2, H0, H1, acc);
        if (++z >= 10) break;
    }

    // block reduction: wave64 shuffle, then across the 4 waves via LDS
    for (int o = 32; o > 0; o >>= 1) acc += __shfl_down(acc, o, 64);
    __shared__ float sred[BDIM / 64];
    __shared__ int isLast;
    const int lane = threadIdx.x & 63, wv = threadIdx.x >> 6;
    if (lane == 0) sred[wv] = acc;
    __syncthreads();
    if (threadIdx.x == 0) {
        float t = 0.f;
#pragma unroll
        for (int i = 0; i < BDIM / 64; ++i) t += sred[i];
        const size_t pidx = (size_t)b * 720 + (size_t)zc * 120 + blockIdx.x;
        __hip_atomic_store(&partial[pidx], t, __ATOMIC_RELAXED,
                           __HIP_MEMORY_SCOPE_AGENT);
        const unsigned old = __hip_atomic_fetch_add(counter, 1u, __ATOMIC_ACQ_REL,
                                                    __HIP_MEMORY_SCOPE_AGENT);
        isLast = (old == NPART - 1u) ? 1 : 0;
    }
    __syncthreads();

    if (isLast) {
        // final reduction of all 1440 partials in double, write the mean
        double a = 0.0;
        for (unsigned i = threadIdx.x; i < NPART; i += BDIM)
            a += (double)__hip_atomic_load(&partial[i], __ATOMIC_RELAXED,
                                           __HIP_MEMORY_SCOPE_AGENT);
        for (int o = 32; o > 0; o >>= 1) a += __shfl_down(a, o, 64);
        __shared__ double sd[BDIM / 64];
        if (lane == 0) sd[wv] = a;
        __syncthreads();
        if (threadIdx.x == 0) {
            double t = 0.0;
#pragma unroll
            for (int i = 0; i < BDIM / 64; ++i) t += sd[i];
            out[0] = (float)(t / 13824000.0);
        }
    }
}

extern "C" void kernel_launch(void* const* d_in, const int* in_sizes, int n_in,
                              void* d_out, int out_size, void* d_ws, size_t ws_size,
                              hipStream_t stream)
{
    const float* pred = (const float*)d_in[0];
    const float* hr   = (const float*)d_in[1];

    // ws layout: [0, 5.76KB): 1440 float partials (fully overwritten each call)
    //            [32KB): unsigned last-block counter (zeroed by P1 each call)
    //            [64KB, ...): fp16 mag buffers
    float* partial = (float*)d_ws;
    unsigned* counter = (unsigned*)((char*)d_ws + 32768);
    __half* magBase = (__half*)((char*)d_ws + 65536);

    const size_t needMerged = 65536 + 4 * MAGSZ * sizeof(__half);  // ~58.3 MB

    if (ws_size >= needMerged) {
        // Merged path: buffers [P b0][P b1][H b0][H b1], stride MAGSZ per batch.
        __half* magP = magBase;
        __half* magH = magBase + 2 * MAGSZ;
        sobel_mag_stream<<<dim3(64, 8, 4), BDIM, 0, stream>>>(
            pred, hr, magP, magH, MAGSZ, 0, counter);
        sobel2_stream<<<dim3(120, 6, 2), BDIM, 0, stream>>>(
            magP, magH, MAGSZ, 0, partial, counter, (float*)d_out);
    } else {
        // Fallback (proven R4 shape): 2 buffers, per-batch serial chain.
        __half* magP = magBase;
        __half* magH = magBase + MAGSZ;
        for (int b = 0; b < 2; ++b) {
            sobel_mag_stream<<<dim3(64, 8, 2), BDIM, 0, stream>>>(
                pred, hr, magP, magH, 0, b, counter);
            sobel2_stream<<<dim3(120, 6, 1), BDIM, 0, stream>>>(
                magP, magH, 0, b, partial, counter, (float*)d_out);
        }
    }
}

// Round 2
// 262.882 us; speedup vs baseline: 1.0090x; 1.0090x over previous
//
#include <hip/hip_runtime.h>
#include <hip/hip_fp16.h>

// Problem geometry: inputs (B=2, D=64, H=64, W=64, C=32) fp32, C innermost.
// Pass1: Sobel (VALID) -> mag = sqrt(gx^2+gy^2+gz^2) at 62^3 per (b,c)
// Pass2: Sobel on mag -> out = sqrt(gx^2+gy^2) + gz^2 at 60^3
// Result: mean(|out_pred - out_hr|) over 2*32*60^3 = 13,824,000 elems.
//
// R6: explicit software pipelining. R5 counters: VALUBusy ~35% and occupancy
// ~36% did NOT move when the grid doubled -> waves stall in lockstep; each
// plane-step serializes (issue loads -> wait -> compute). Fix: split plane
// processing into load (into a named register buffer) and math (consume), and
// prefetch plane z+3 into the free buffer BEFORE consuming plane z+2. L-buffer
// ping-pong (period 2) x W rotation (period 3) -> 6-stage unrolled loop, all
// compile-time indices. Launch structure kept from R5 (merged batches, fused
// finalize): P1 grid (64,8,4), P2 grid (120,6,2).

constexpr int BDIM = 256;
constexpr size_t IN_B = 8388608;   // 64*64*64*32 elements per batch
constexpr int IN_D = 131072;       // 64*64*32
constexpr int IN_H = 2048;         // 64*32
constexpr int M = 62;              // mag spatial dim
constexpr int F = 60;              // final spatial dim
constexpr int C = 32;
constexpr int MROW = M * C;                      // 1984
constexpr size_t MAGSZ = (size_t)M * M * MROW;   // halves per buffer
constexpr size_t PLANE = (size_t)M * MROW;       // halves per mag z-plane
constexpr unsigned NPART = 1440;                 // total partials (both batches)

__device__ __forceinline__ float2 ld2(const float* p) {
    return *reinterpret_cast<const float2*>(p);
}

// ================= Pass 1: input -> fp16 magnitude, z-streamed =================
struct P1L { float2 a[6], b[6], c[6]; };   // raw loads for one z-plane (18 x 8B)
struct P1W { float2 A[4], B[4], C[4]; };   // per-plane partials for 4 output rows

__device__ __forceinline__ void p1_load(const float* __restrict__ col, size_t zoff,
                                        const int jr[6], P1L& L)
{
#pragma unroll
    for (int j = 0; j < 6; ++j) {
        const float* p = col + zoff + jr[j];
        L.a[j] = ld2(p); L.b[j] = ld2(p + C); L.c[j] = ld2(p + 2 * C);
    }
}

__device__ __forceinline__ void p1_math(const P1L& L, P1W& W)
{
    float2 SX[6], DX[6];
#pragma unroll
    for (int j = 0; j < 6; ++j) {
        SX[j] = make_float2(L.a[j].x + 2.f * L.b[j].x + L.c[j].x,
                            L.a[j].y + 2.f * L.b[j].y + L.c[j].y);
        DX[j] = make_float2(L.c[j].x - L.a[j].x, L.c[j].y - L.a[j].y);
    }
#pragma unroll
    for (int k = 0; k < 4; ++k) {
        W.A[k] = make_float2(SX[k].x + 2.f * SX[k+1].x + SX[k+2].x,
                             SX[k].y + 2.f * SX[k+1].y + SX[k+2].y);
        W.B[k] = make_float2(SX[k+2].x - SX[k].x, SX[k+2].y - SX[k].y);
        W.C[k] = make_float2(DX[k].x + 2.f * DX[k+1].x + DX[k+2].x,
                             DX[k].y + 2.f * DX[k+1].y + DX[k+2].y);
    }
}

__device__ __forceinline__ void p1_emit(const P1W& W0, const P1W& W1, const P1W& W2,
                                        __half* __restrict__ mag, size_t cb,
                                        int z, int y0, int kmax, bool xok)
{
    if (!xok) return;
#pragma unroll
    for (int k = 0; k < 4; ++k) {
        if (k < kmax) {
            float gxx = W2.A[k].x - W0.A[k].x;
            float gxy = W2.A[k].y - W0.A[k].y;
            float gyx = W0.B[k].x + 2.f * W1.B[k].x + W2.B[k].x;
            float gyy = W0.B[k].y + 2.f * W1.B[k].y + W2.B[k].y;
            float gzx = W0.C[k].x + 2.f * W1.C[k].x + W2.C[k].x;
            float gzy = W0.C[k].y + 2.f * W1.C[k].y + W2.C[k].y;
            float mx = sqrtf(gxx * gxx + gyx * gyx + gzx * gzx);
            float my = sqrtf(gxy * gxy + gyy * gyy + gzy * gzy);
            *reinterpret_cast<__half2*>(mag + ((size_t)z * M + (y0 + k)) * MROW + cb)
                = __floats2half2_rn(mx, my);
        }
    }
}

// grid: (64, 8, 2*nb). blockIdx.z = (b-b0)*2 + isHr.
__global__ __launch_bounds__(BDIM) void sobel_mag_stream(
    const float* __restrict__ pred, const float* __restrict__ hr,
    __half* __restrict__ magP, __half* __restrict__ magH,
    size_t magBStride, int b0, unsigned* __restrict__ counter)
{
    if (b0 == 0 && blockIdx.x == 0 && blockIdx.y == 0 && blockIdx.z == 0 &&
        threadIdx.x == 0)
        *counter = 0u;

    const int xt = blockIdx.x & 3, yt = blockIdx.x >> 2;   // grid.x = 64
    const int zc = blockIdx.y;                             // [0,8)
    const int bz = blockIdx.z;
    const int b  = b0 + (bz >> 1);
    const float* __restrict__ in  = (bz & 1) ? hr : pred;
    __half*      __restrict__ mag = ((bz & 1) ? magH : magP)
                                    + (size_t)(bz >> 1) * magBStride;

    const int y0 = yt * 4;
    const int z0 = zc * 8;
    const int zn = min(8, M - z0);        // 8 or 6
    const int kmax = min(4, M - y0);      // 4 or (last tile) 2
    const int xraw = xt * 16 + (threadIdx.x >> 4);
    const bool xok = xraw < M;
    const int x = min(xraw, M - 1);
    const int c2 = (threadIdx.x & 15) << 1;

    int jr[6];
#pragma unroll
    for (int j = 0; j < 6; ++j) jr[j] = min(y0 + j, 63) * IN_H;

    const float* col = in + (size_t)b * IN_B + (size_t)x * C + c2;
    const size_t cb = (size_t)x * C + c2;

    // zoff for input plane zz, clamped in-bounds (prefetch beyond the last
    // consumed plane is never used, just must not fault)
#define P1ZO(zz) ((size_t)min((zz), 63) * IN_D)

    P1L La, Lb;
    P1W W0, W1, W2;
    p1_load(col, P1ZO(z0 + 0), jr, La);
    p1_load(col, P1ZO(z0 + 1), jr, Lb);
    p1_math(La, W0);
    p1_load(col, P1ZO(z0 + 2), jr, La);
    p1_math(Lb, W1);

    // step i: prefetch plane z0+i+3 into free buffer, consume other into
    // W[(i+2)%3], emit(W[i%3], W[(i+1)%3], W[(i+2)%3]) at z = z0+i.
    int z = 0;
    while (true) {
        p1_load(col, P1ZO(z0 + z + 3), jr, Lb);
        p1_math(La, W2);
        p1_emit(W0, W1, W2, mag, cb, z0 + z, y0, kmax, xok);
        if (++z >= zn) break;
        p1_load(col, P1ZO(z0 + z + 3), jr, La);
        p1_math(Lb, W0);
        p1_emit(W1, W2, W0, mag, cb, z0 + z, y0, kmax, xok);
        if (++z >= zn) break;
        p1_load(col, P1ZO(z0 + z + 3), jr, Lb);
        p1_math(La, W1);
        p1_emit(W2, W0, W1, mag, cb, z0 + z, y0, kmax, xok);
        if (++z >= zn) break;
        p1_load(col, P1ZO(z0 + z + 3), jr, La);
        p1_math(Lb, W2);
        p1_emit(W0, W1, W2, mag, cb, z0 + z, y0, kmax, xok);
        if (++z >= zn) break;
        p1_load(col, P1ZO(z0 + z + 3), jr, Lb);
        p1_math(La, W0);
        p1_emit(W1, W2, W0, mag, cb, z0 + z, y0, kmax, xok);
        if (++z >= zn) break;
        p1_load(col, P1ZO(z0 + z + 3), jr, La);
        p1_math(Lb, W1);
        p1_emit(W2, W0, W1, mag, cb, z0 + z, y0, kmax, xok);
        if (++z >= zn) break;
    }
#undef P1ZO
}

// ============ Pass 2: mag -> final, diff, partial sums, z-streamed ============
struct P2L { __half2 a[4], b[4], c[4]; };  // raw loads for one z-plane (12 x 4B)
struct P2W { float2 A[2], B[2], C[2]; };

__device__ __forceinline__ void p2_load(const __half* __restrict__ col, size_t zoff,
                                        P2L& L)
{
#pragma unroll
    for (int j = 0; j < 4; ++j) {
        const __half* p = col + zoff + (size_t)j * MROW;
        L.a[j] = *reinterpret_cast<const __half2*>(p);
        L.b[j] = *reinterpret_cast<const __half2*>(p + C);
        L.c[j] = *reinterpret_cast<const __half2*>(p + 2 * C);
    }
}

__device__ __forceinline__ void p2_math(const P2L& L, P2W& W)
{
    float2 SX[4], DX[4];
#pragma unroll
    for (int j = 0; j < 4; ++j) {
        float2 a = __half22float2(L.a[j]);
        float2 b = __half22float2(L.b[j]);
        float2 c = __half22float2(L.c[j]);
        SX[j] = make_float2(a.x + 2.f * b.x + c.x, a.y + 2.f * b.y + c.y);
        DX[j] = make_float2(c.x - a.x, c.y - a.y);
    }
#pragma unroll
    for (int k = 0; k < 2; ++k) {
        W.A[k] = make_float2(SX[k].x + 2.f * SX[k+1].x + SX[k+2].x,
                             SX[k].y + 2.f * SX[k+1].y + SX[k+2].y);
        W.B[k] = make_float2(SX[k+2].x - SX[k].x, SX[k+2].y - SX[k].y);
        W.C[k] = make_float2(DX[k].x + 2.f * DX[k+1].x + DX[k+2].x,
                             DX[k].y + 2.f * DX[k+1].y + DX[k+2].y);
    }
}

__device__ __forceinline__ void p2_emit(const P2W& P0, const P2W& P1, const P2W& P2,
                                        const P2W& H0, const P2W& H1, const P2W& H2,
                                        float& acc)
{
#pragma unroll
    for (int k = 0; k < 2; ++k) {
        float gxPx = P2.A[k].x - P0.A[k].x;
        float gxPy = P2.A[k].y - P0.A[k].y;
        float gyPx = P0.B[k].x + 2.f * P1.B[k].x + P2.B[k].x;
        float gyPy = P0.B[k].y + 2.f * P1.B[k].y + P2.B[k].y;
        float gzPx = P0.C[k].x + 2.f * P1.C[k].x + P2.C[k].x;
        float gzPy = P0.C[k].y + 2.f * P1.C[k].y + P2.C[k].y;
        float gxHx = H2.A[k].x - H0.A[k].x;
        float gxHy = H2.A[k].y - H0.A[k].y;
        float gyHx = H0.B[k].x + 2.f * H1.B[k].x + H2.B[k].x;
        float gyHy = H0.B[k].y + 2.f * H1.B[k].y + H2.B[k].y;
        float gzHx = H0.C[k].x + 2.f * H1.C[k].x + H2.C[k].x;
        float gzHy = H0.C[k].y + 2.f * H1.C[k].y + H2.C[k].y;
        float oPx = sqrtf(gxPx * gxPx + gyPx * gyPx) + gzPx * gzPx;
        float oPy = sqrtf(gxPy * gxPy + gyPy * gyPy) + gzPy * gzPy;
        float oHx = sqrtf(gxHx * gxHx + gyHx * gyHx) + gzHx * gzHx;
        float oHy = sqrtf(gxHy * gxHy + gyHy * gyHy) + gzHy * gzHy;
        acc += fabsf(oPx - oHx) + fabsf(oPy - oHy);
    }
}

// grid: (120, 6, nb). Last block (device-wide, agent-scope atomic count) does
// the final 1440-partial reduction and writes the mean.
__global__ __launch_bounds__(BDIM) void sobel2_stream(
    const __half* __restrict__ magP, const __half* __restrict__ magH,
    size_t magBStride, int b0,
    float* __restrict__ partial, unsigned* __restrict__ counter,
    float* __restrict__ out)
{
    const int xt = blockIdx.x & 3, yt = blockIdx.x >> 2;   // grid.x = 120
    const int zc = blockIdx.y;                             // [0,6)
    const int bb = blockIdx.z;
    const int b  = b0 + bb;
    const int y0 = yt * 2;
    const int z0 = zc * 10;
    const int xraw = xt * 16 + (threadIdx.x >> 4);
    const bool xok = xraw < F;
    const int x = min(xraw, F - 1);
    const int c2 = (threadIdx.x & 15) << 1;

    const size_t colo = (size_t)y0 * MROW + (size_t)x * C + c2;
    const __half* colP = magP + (size_t)bb * magBStride + colo;
    const __half* colH = magH + (size_t)bb * magBStride + colo;

#define P2ZO(zz) ((size_t)min((zz), M - 1) * PLANE)

    P2L LPa, LPb, LHa, LHb;
    P2W P0, P1, P2, H0, H1, H2;
    p2_load(colP, P2ZO(z0 + 0), LPa); p2_load(colH, P2ZO(z0 + 0), LHa);
    p2_load(colP, P2ZO(z0 + 1), LPb); p2_load(colH, P2ZO(z0 + 1), LHb);
    p2_math(LPa, P0); p2_math(LHa, H0);
    p2_load(colP, P2ZO(z0 + 2), LPa); p2_load(colH, P2ZO(z0 + 2), LHa);
    p2_math(LPb, P1); p2_math(LHb, H1);

    float acc = 0.f;
    int z = 0;
    while (true) {
        p2_load(colP, P2ZO(z0 + z + 3), LPb); p2_load(colH, P2ZO(z0 + z + 3), LHb);
        p2_math(LPa, P2); p2_math(LHa, H2);
        if (xok) p2_emit(P0, P1, P2, H0, H1, H2, acc);
        if (++z >= 10) break;
        p2_load(colP, P2ZO(z0 + z + 3), LPa); p2_load(colH, P2ZO(z0 + z + 3), LHa);
        p2_math(LPb, P0); p2_math(LHb, H0);
        if (xok) p2_emit(P1, P2, P0, H1, H2, H0, acc);
        if (++z >= 10) break;
        p2_load(colP, P2ZO(z0 + z + 3), LPb); p2_load(colH, P2ZO(z0 + z + 3), LHb);
        p2_math(LPa, P1); p2_math(LHa, H1);
        if (xok) p2_emit(P2, P0, P1, H2, H0, H1, acc);
        if (++z >= 10) break;
        p2_load(colP, P2ZO(z0 + z + 3), LPa); p2_load(colH, P2ZO(z0 + z + 3), LHa);
        p2_math(LPb, P2); p2_math(LHb, H2);
        if (xok) p2_emit(P0, P1, P2, H0, H1, H2, acc);
        if (++z >= 10) break;
        p2_load(colP, P2ZO(z0 + z + 3), LPb); p2_load(colH, P2ZO(z0 + z + 3), LHb);
        p2_math(LPa, P0); p2_math(LHa, H0);
        if (xok) p2_emit(P1, P2, P0, H1, H2, H0, acc);
        if (++z >= 10) break;
        p2_load(colP, P2ZO(z0 + z + 3), LPa); p2_load(colH, P2ZO(z0 + z + 3), LHa);
        p2_math(LPb, P1); p2_math(LHb, H1);
        if (xok) p2_emit(P2, P0, P1, H2, H0, H1, acc);
        if (++z >= 10) break;
    }
#undef P2ZO

    // block reduction: wave64 shuffle, then across the 4 waves via LDS
    for (int o = 32; o > 0; o >>= 1) acc += __shfl_down(acc, o, 64);
    __shared__ float sred[BDIM / 64];
    __shared__ int isLast;
    const int lane = threadIdx.x & 63, wv = threadIdx.x >> 6;
    if (lane == 0) sred[wv] = acc;
    __syncthreads();
    if (threadIdx.x == 0) {
        float t = 0.f;
#pragma unroll
        for (int i = 0; i < BDIM / 64; ++i) t += sred[i];
        const size_t pidx = (size_t)b * 720 + (size_t)zc * 120 + blockIdx.x;
        __hip_atomic_store(&partial[pidx], t, __ATOMIC_RELAXED,
                           __HIP_MEMORY_SCOPE_AGENT);
        const unsigned old = __hip_atomic_fetch_add(counter, 1u, __ATOMIC_ACQ_REL,
                                                    __HIP_MEMORY_SCOPE_AGENT);
        isLast = (old == NPART - 1u) ? 1 : 0;
    }
    __syncthreads();

    if (isLast) {
        double a = 0.0;
        for (unsigned i = threadIdx.x; i < NPART; i += BDIM)
            a += (double)__hip_atomic_load(&partial[i], __ATOMIC_RELAXED,
                                           __HIP_MEMORY_SCOPE_AGENT);
        for (int o = 32; o > 0; o >>= 1) a += __shfl_down(a, o, 64);
        __shared__ double sd[BDIM / 64];
        if (lane == 0) sd[wv] = a;
        __syncthreads();
        if (threadIdx.x == 0) {
            double t = 0.0;
#pragma unroll
            for (int i = 0; i < BDIM / 64; ++i) t += sd[i];
            out[0] = (float)(t / 13824000.0);
        }
    }
}

extern "C" void kernel_launch(void* const* d_in, const int* in_sizes, int n_in,
                              void* d_out, int out_size, void* d_ws, size_t ws_size,
                              hipStream_t stream)
{
    const float* pred = (const float*)d_in[0];
    const float* hr   = (const float*)d_in[1];

    // ws layout: [0, 5.76KB): 1440 float partials
    //            [32KB): unsigned last-block counter (zeroed by P1 each call)
    //            [64KB, ...): fp16 mag buffers
    float* partial = (float*)d_ws;
    unsigned* counter = (unsigned*)((char*)d_ws + 32768);
    __half* magBase = (__half*)((char*)d_ws + 65536);

    const size_t needMerged = 65536 + 4 * MAGSZ * sizeof(__half);  // ~58.3 MB

    if (ws_size >= needMerged) {
        __half* magP = magBase;
        __half* magH = magBase + 2 * MAGSZ;
        sobel_mag_stream<<<dim3(64, 8, 4), BDIM, 0, stream>>>(
            pred, hr, magP, magH, MAGSZ, 0, counter);
        sobel2_stream<<<dim3(120, 6, 2), BDIM, 0, stream>>>(
            magP, magH, MAGSZ, 0, partial, counter, (float*)d_out);
    } else {
        __half* magP = magBase;
        __half* magH = magBase + MAGSZ;
        for (int b = 0; b < 2; ++b) {
            sobel_mag_stream<<<dim3(64, 8, 2), BDIM, 0, stream>>>(
                pred, hr, magP, magH, 0, b, counter);
            sobel2_stream<<<dim3(120, 6, 1), BDIM, 0, stream>>>(
                magP, magH, 0, b, partial, counter, (float*)d_out);
        }
    }
}

// Round 3
// 257.526 us; speedup vs baseline: 1.0299x; 1.0208x over previous
//
#include <hip/hip_runtime.h>
#include <hip/hip_fp16.h>

// Problem geometry: inputs (B=2, D=64, H=64, W=64, C=32) fp32, C innermost.
// Pass1: Sobel (VALID) -> mag = sqrt(gx^2+gy^2+gz^2) at 62^3 per (b,c)
// Pass2: Sobel on mag -> out = sqrt(gx^2+gy^2) + gz^2 at 60^3
// Result: mean(|out_pred - out_hr|) over 2*32*60^3 = 13,824,000 elems.
//
// R7: wide loads. Evidence R4-R6: HBM rate pinned at ~2.1 TB/s across all
// launch geometries, FETCH = exactly input size, all pipes <40%, perf
// invariant to TLP (R5) and ILP (R6) -> per-CU BW cap = bytes-in-flight /
// latency. The 6.3 TB/s copy reference uses 16B/lane; we used 8B. Fix: remap
// P1 lanes to 4 channels/thread so every input load is a float4 (1 KiB per
// wave-load) -> 2x bytes per outstanding VMEM entry, half the VMEM instrs.
// Tile 32x-out x 2y-out per block (no clamps anywhere). P2 kept at proven R4
// shape (one variable at a time). Launches: per-batch P1->P2 chain (keeps mag
// L3-resident for P2; R5's merge pushed working set past L3 and regressed),
// finalize fused into globally-last P2 block. Counter zeroing now agent-scope
// atomic (plain store relied on cross-XCD L2 coherence).

constexpr int BDIM = 256;
constexpr size_t IN_B = 8388608;   // 64*64*64*32 elements per batch
constexpr int IN_D = 131072;       // 64*64*32
constexpr int IN_H = 2048;         // 64*32
constexpr int M = 62;              // mag spatial dim
constexpr int F = 60;              // final spatial dim
constexpr int C = 32;
constexpr int MROW = M * C;                      // 1984
constexpr size_t MAGSZ = (size_t)M * M * MROW;   // halves per buffer
constexpr size_t PLANE = (size_t)M * MROW;       // halves per mag z-plane
constexpr unsigned NPART = 1440;                 // total partials (both batches)

__device__ __forceinline__ float4 ld4(const float* p) {
    return *reinterpret_cast<const float4*>(p);
}
__device__ __forceinline__ float2 ldh2(const __half* p) {
    return __half22float2(*reinterpret_cast<const __half2*>(p));
}
// s + 2m + e, componentwise
__device__ __forceinline__ float4 sm3(float4 a, float4 b, float4 c) {
    return make_float4(a.x + 2.f * b.x + c.x, a.y + 2.f * b.y + c.y,
                       a.z + 2.f * b.z + c.z, a.w + 2.f * b.w + c.w);
}
// c - a, componentwise
__device__ __forceinline__ float4 df2(float4 a, float4 c) {
    return make_float4(c.x - a.x, c.y - a.y, c.z - a.z, c.w - a.w);
}

// ================= Pass 1: input -> fp16 magnitude, z-streamed =================
// Thread owns 4 channels at one x; block = 32 x-outputs (8 c-groups) x 2 y-outputs.
struct P1W { float4 A[2], B[2], C[2]; };   // per-plane partials, 2 output rows

__device__ __forceinline__ void p1_plane(const float* __restrict__ col, size_t zoff,
                                         P1W& W)
{
    float4 S[4], D[4];
#pragma unroll
    for (int r = 0; r < 4; ++r) {
        const float* p = col + zoff + (size_t)r * IN_H;
        float4 a = ld4(p), b = ld4(p + C), c = ld4(p + 2 * C);
        S[r] = sm3(a, b, c);       // x-smooth
        D[r] = df2(a, c);          // x-diff
    }
#pragma unroll
    for (int k = 0; k < 2; ++k) {
        W.A[k] = sm3(S[k], S[k+1], S[k+2]);   // y-smooth(x-smooth)
        W.B[k] = df2(S[k], S[k+2]);           // y-diff(x-smooth)
        W.C[k] = sm3(D[k], D[k+1], D[k+2]);   // y-smooth(x-diff)
    }
}

__device__ __forceinline__ void p1_emit(const P1W& W0, const P1W& W1, const P1W& W2,
                                        __half* __restrict__ mag, size_t cb,
                                        int z, int y0, bool wr)
{
    if (!wr) return;
#pragma unroll
    for (int k = 0; k < 2; ++k) {
        float4 gx = df2(W0.A[k], W2.A[k]);            // z-diff
        float4 gy = sm3(W0.B[k], W1.B[k], W2.B[k]);   // z-smooth
        float4 gz = sm3(W0.C[k], W1.C[k], W2.C[k]);   // z-smooth
        float mx = sqrtf(gx.x * gx.x + gy.x * gy.x + gz.x * gz.x);
        float my = sqrtf(gx.y * gx.y + gy.y * gy.y + gz.y * gz.y);
        float mz = sqrtf(gx.z * gx.z + gy.z * gy.z + gz.z * gz.z);
        float mw = sqrtf(gx.w * gx.w + gy.w * gy.w + gz.w * gz.w);
        union { __half2 h[2]; float2 f; } u;
        u.h[0] = __floats2half2_rn(mx, my);
        u.h[1] = __floats2half2_rn(mz, mw);
        *reinterpret_cast<float2*>(mag + ((size_t)z * M + (y0 + k)) * MROW + cb)
            = u.f;
    }
}

// grid: (62, 8, 2). blockIdx.x = yt*2 + xt; blockIdx.z = isHr.
__global__ __launch_bounds__(BDIM) void sobel_mag_v7(
    const float* __restrict__ pred, const float* __restrict__ hr,
    __half* __restrict__ magP, __half* __restrict__ magH,
    int b, unsigned* __restrict__ counter, int zeroCtr)
{
    if (zeroCtr && blockIdx.x == 0 && blockIdx.y == 0 && blockIdx.z == 0 &&
        threadIdx.x == 0)
        __hip_atomic_store(counter, 0u, __ATOMIC_RELAXED,
                           __HIP_MEMORY_SCOPE_AGENT);

    const int xt = blockIdx.x & 1, yt = blockIdx.x >> 1;   // xt in {0,1}, yt in [0,31)
    const int zc = blockIdx.y;                             // [0,8)
    const float* __restrict__ in  = blockIdx.z ? hr   : pred;
    __half*      __restrict__ mag = blockIdx.z ? magH : magP;

    const int c4 = (threadIdx.x & 7) << 2;   // channel base: 0,4,..,28
    const int xl = threadIdx.x >> 3;         // 0..31
    const int x0 = xt * 30;
    const int x  = x0 + xl;                  // output x in [0,62)
    const bool wr = (xt == 0) || (xl >= 2);  // tile1 skips duplicated x=30,31
    const int y0 = yt * 2;                   // output rows y0, y0+1 (rows y0..y0+3)
    const int z0 = zc * 8;
    const int zn = min(8, M - z0);           // 8, last chunk 6

    // input cols x, x+1, x+2 (max 63), rows y0..y0+3 (max 63) -> no clamps.
    const float* col = in + (size_t)b * IN_B + (size_t)y0 * IN_H
                          + (size_t)x * C + c4;
    const size_t cb = (size_t)x * C + c4;

    P1W W0, W1, W2;
    p1_plane(col, (size_t)(z0 + 0) * IN_D, W0);
    p1_plane(col, (size_t)(z0 + 1) * IN_D, W1);
    int z = 0;
    while (true) {
        p1_plane(col, (size_t)(z0 + z + 2) * IN_D, W2);
        p1_emit(W0, W1, W2, mag, cb, z0 + z, y0, wr);
        if (++z >= zn) break;
        p1_plane(col, (size_t)(z0 + z + 2) * IN_D, W0);
        p1_emit(W1, W2, W0, mag, cb, z0 + z, y0, wr);
        if (++z >= zn) break;
        p1_plane(col, (size_t)(z0 + z + 2) * IN_D, W1);
        p1_emit(W2, W0, W1, mag, cb, z0 + z, y0, wr);
        if (++z >= zn) break;
    }
}

// ============ Pass 2: mag -> final, diff, partial sums, z-streamed ============
// Proven R4 shape: 2 channels/thread, x-tile 16, y-tile 2, z-tile 10.
struct P2W { float2 A[2], B[2], C[2]; };

__device__ __forceinline__ void p2_plane(const __half* __restrict__ col, size_t zoff,
                                         P2W& W)
{
    float2 SX[4], DX[4];
#pragma unroll
    for (int j = 0; j < 4; ++j) {
        const __half* p = col + zoff + (size_t)j * MROW;
        float2 a = ldh2(p), b = ldh2(p + C), c = ldh2(p + 2 * C);
        SX[j] = make_float2(a.x + 2.f * b.x + c.x, a.y + 2.f * b.y + c.y);
        DX[j] = make_float2(c.x - a.x, c.y - a.y);
    }
#pragma unroll
    for (int k = 0; k < 2; ++k) {
        W.A[k] = make_float2(SX[k].x + 2.f * SX[k+1].x + SX[k+2].x,
                             SX[k].y + 2.f * SX[k+1].y + SX[k+2].y);
        W.B[k] = make_float2(SX[k+2].x - SX[k].x, SX[k+2].y - SX[k].y);
        W.C[k] = make_float2(DX[k].x + 2.f * DX[k+1].x + DX[k+2].x,
                             DX[k].y + 2.f * DX[k+1].y + DX[k+2].y);
    }
}

__device__ __forceinline__ void p2_emit(const P2W& P0, const P2W& P1, const P2W& P2,
                                        const P2W& H0, const P2W& H1, const P2W& H2,
                                        float& acc)
{
#pragma unroll
    for (int k = 0; k < 2; ++k) {
        float gxPx = P2.A[k].x - P0.A[k].x;
        float gxPy = P2.A[k].y - P0.A[k].y;
        float gyPx = P0.B[k].x + 2.f * P1.B[k].x + P2.B[k].x;
        float gyPy = P0.B[k].y + 2.f * P1.B[k].y + P2.B[k].y;
        float gzPx = P0.C[k].x + 2.f * P1.C[k].x + P2.C[k].x;
        float gzPy = P0.C[k].y + 2.f * P1.C[k].y + P2.C[k].y;
        float gxHx = H2.A[k].x - H0.A[k].x;
        float gxHy = H2.A[k].y - H0.A[k].y;
        float gyHx = H0.B[k].x + 2.f * H1.B[k].x + H2.B[k].x;
        float gyHy = H0.B[k].y + 2.f * H1.B[k].y + H2.B[k].y;
        float gzHx = H0.C[k].x + 2.f * H1.C[k].x + H2.C[k].x;
        float gzHy = H0.C[k].y + 2.f * H1.C[k].y + H2.C[k].y;
        float oPx = sqrtf(gxPx * gxPx + gyPx * gyPx) + gzPx * gzPx;
        float oPy = sqrtf(gxPy * gxPy + gyPy * gyPy) + gzPy * gzPy;
        float oHx = sqrtf(gxHx * gxHx + gyHx * gyHx) + gzHx * gzHx;
        float oHy = sqrtf(gxHy * gxHy + gyHy * gyHy) + gzHy * gzHy;
        acc += fabsf(oPx - oHx) + fabsf(oPy - oHy);
    }
}

// grid: (120, 6). Globally-last block (agent-scope atomic count over both
// batches) does the final 1440-partial reduction and writes the mean.
__global__ __launch_bounds__(BDIM) void sobel2_v7(
    const __half* __restrict__ magP, const __half* __restrict__ magH,
    int b, float* __restrict__ partial, unsigned* __restrict__ counter,
    float* __restrict__ out)
{
    const int xt = blockIdx.x & 3, yt = blockIdx.x >> 2;   // grid.x = 120
    const int zc = blockIdx.y;                             // [0,6)
    const int y0 = yt * 2;
    const int z0 = zc * 10;
    const int xraw = xt * 16 + (threadIdx.x >> 4);
    const bool xok = xraw < F;
    const int x = min(xraw, F - 1);
    const int c2 = (threadIdx.x & 15) << 1;

    const size_t colo = (size_t)y0 * MROW + (size_t)x * C + c2;
    const __half* colP = magP + colo;
    const __half* colH = magH + colo;

    P2W P0, P1, P2, H0, H1, H2;
    p2_plane(colP, (size_t)(z0 + 0) * PLANE, P0);
    p2_plane(colH, (size_t)(z0 + 0) * PLANE, H0);
    p2_plane(colP, (size_t)(z0 + 1) * PLANE, P1);
    p2_plane(colH, (size_t)(z0 + 1) * PLANE, H1);
    float acc = 0.f;
    int z = 0;
    while (true) {
        p2_plane(colP, (size_t)(z0 + z + 2) * PLANE, P2);
        p2_plane(colH, (size_t)(z0 + z + 2) * PLANE, H2);
        if (xok) p2_emit(P0, P1, P2, H0, H1, H2, acc);
        if (++z >= 10) break;
        p2_plane(colP, (size_t)(z0 + z + 2) * PLANE, P0);
        p2_plane(colH, (size_t)(z0 + z + 2) * PLANE, H0);
        if (xok) p2_emit(P1, P2, P0, H1, H2, H0, acc);
        if (++z >= 10) break;
        p2_plane(colP, (size_t)(z0 + z + 2) * PLANE, P1);
        p2_plane(colH, (size_t)(z0 + z + 2) * PLANE, H1);
        if (xok) p2_emit(P2, P0, P1, H2, H0, H1, acc);
        if (++z >= 10) break;
    }

    // block reduction: wave64 shuffle, then across the 4 waves via LDS
    for (int o = 32; o > 0; o >>= 1) acc += __shfl_down(acc, o, 64);
    __shared__ float sred[BDIM / 64];
    __shared__ int isLast;
    const int lane = threadIdx.x & 63, wv = threadIdx.x >> 6;
    if (lane == 0) sred[wv] = acc;
    __syncthreads();
    if (threadIdx.x == 0) {
        float t = 0.f;
#pragma unroll
        for (int i = 0; i < BDIM / 64; ++i) t += sred[i];
        const size_t pidx = (size_t)b * 720 + (size_t)zc * 120 + blockIdx.x;
        __hip_atomic_store(&partial[pidx], t, __ATOMIC_RELAXED,
                           __HIP_MEMORY_SCOPE_AGENT);
        const unsigned old = __hip_atomic_fetch_add(counter, 1u, __ATOMIC_ACQ_REL,
                                                    __HIP_MEMORY_SCOPE_AGENT);
        isLast = (old == NPART - 1u) ? 1 : 0;
    }
    __syncthreads();

    if (isLast) {
        double a = 0.0;
        for (unsigned i = threadIdx.x; i < NPART; i += BDIM)
            a += (double)__hip_atomic_load(&partial[i], __ATOMIC_RELAXED,
                                           __HIP_MEMORY_SCOPE_AGENT);
        for (int o = 32; o > 0; o >>= 1) a += __shfl_down(a, o, 64);
        __shared__ double sd[BDIM / 64];
        if (lane == 0) sd[wv] = a;
        __syncthreads();
        if (threadIdx.x == 0) {
            double t = 0.0;
#pragma unroll
            for (int i = 0; i < BDIM / 64; ++i) t += sd[i];
            out[0] = (float)(t / 13824000.0);
        }
    }
}

extern "C" void kernel_launch(void* const* d_in, const int* in_sizes, int n_in,
                              void* d_out, int out_size, void* d_ws, size_t ws_size,
                              hipStream_t stream)
{
    const float* pred = (const float*)d_in[0];
    const float* hr   = (const float*)d_in[1];

    // ws layout: [0, 5.76KB): 1440 float partials
    //            [32KB): unsigned last-block counter (zeroed by P1(b0))
    //            [64KB, ...): 2 fp16 mag buffers (~29.2 MB), reused per batch
    float* partial = (float*)d_ws;
    unsigned* counter = (unsigned*)((char*)d_ws + 32768);
    __half* magP = (__half*)((char*)d_ws + 65536);
    __half* magH = magP + MAGSZ;

    for (int b = 0; b < 2; ++b) {
        sobel_mag_v7<<<dim3(62, 8, 2), BDIM, 0, stream>>>(
            pred, hr, magP, magH, b, counter, b == 0 ? 1 : 0);
        sobel2_v7<<<dim3(120, 6), BDIM, 0, stream>>>(
            magP, magH, b, partial, counter, (float*)d_out);
    }
}